// Round 2
// baseline (1767.934 us; speedup 1.0000x reference)
//
#include <hip/hip_runtime.h>
#include <math.h>
#include <stdint.h>

#define MMEM 131072
#define KDIM 256
#define NB   1024
#define TOPK 256
#define BETA_F 1e-08f

// Monotone key: unsigned ascending == float ascending
__device__ __forceinline__ uint32_t fkey(float f) {
  uint32_t u = __float_as_uint(f);
  return u ^ ((uint32_t)((int32_t)u >> 31) | 0x80000000u);
}

// ---------------- kernel 1: sum(hist + beta), single block ----------------
__global__ __launch_bounds__(256) void hist_sum_kernel(const float* __restrict__ hist,
                                                       float* __restrict__ out_sum) {
  float s = 0.f;
  for (int i = threadIdx.x; i < MMEM; i += 256) s += hist[i] + BETA_F;
  #pragma unroll
  for (int off = 32; off > 0; off >>= 1) s += __shfl_down(s, off);
  __shared__ float ws[4];
  int lane = threadIdx.x & 63, wid = threadIdx.x >> 6;
  if (lane == 0) ws[wid] = s;
  __syncthreads();
  if (threadIdx.x == 0) {
    float t = 0.f;
    for (int w = 0; w < 4; w++) t += ws[w];
    *out_sum = t;
  }
}

// ---------------- kernel 2: logpc[m] = log(hist[m]+beta) - log(sum) -------
__global__ __launch_bounds__(256) void logpc_kernel(const float* __restrict__ hist,
                                                    const float* __restrict__ sum_ptr,
                                                    float* __restrict__ logpc) {
  int i = blockIdx.x * 256 + threadIdx.x;
  if (i < MMEM) logpc[i] = logf(hist[i] + BETA_F) - logf(*sum_ptr);
}

// ---------------- kernel 3: scores = q @ mk^T + logpc ---------------------
// 64x64 tile, 256 threads, 4x4 micro-tile, BK=64, LDS in [k][m] layout
// so inner loop is 2x ds_read_b128 + 16 v_fma per k-step.
#define LDT 68  // 64 + 4 pad: keeps 16B alignment (68*4=272=17*16), breaks conflicts
__global__ __launch_bounds__(256) void gemm_kernel(const float* __restrict__ q,
                                                   const float* __restrict__ mk,
                                                   const float* __restrict__ logpc,
                                                   float* __restrict__ scores) {
  __shared__ float As[64][LDT];
  __shared__ float Bs[64][LDT];
  const int t  = threadIdx.x;
  const int tx = t & 15;   // col dim
  const int ty = t >> 4;   // row dim
  const size_t row0 = (size_t)blockIdx.x * 64;   // over chunk rows
  const size_t col0 = (size_t)blockIdx.y * 64;   // over M=131072 (2048 tiles)

  float acc[4][4] = {{0.f}};

  for (int kb = 0; kb < KDIM; kb += 64) {
    #pragma unroll
    for (int i = 0; i < 4; i++) {
      int f  = t + 256 * i;      // 0..1023 (1024 float4 = 64x64 tile)
      int r  = f >> 4;           // 0..63
      int k4 = (f & 15) << 2;    // 0..60
      float4 v = *(const float4*)&q [(row0 + r) * KDIM + kb + k4];
      As[k4 + 0][r] = v.x; As[k4 + 1][r] = v.y;
      As[k4 + 2][r] = v.z; As[k4 + 3][r] = v.w;
      float4 w = *(const float4*)&mk[(col0 + r) * KDIM + kb + k4];
      Bs[k4 + 0][r] = w.x; Bs[k4 + 1][r] = w.y;
      Bs[k4 + 2][r] = w.z; Bs[k4 + 3][r] = w.w;
    }
    __syncthreads();
    #pragma unroll
    for (int k = 0; k < 64; k++) {
      float4 av = *(const float4*)&As[k][ty << 2];
      float4 bv = *(const float4*)&Bs[k][tx << 2];
      float a_[4] = {av.x, av.y, av.z, av.w};
      float b_[4] = {bv.x, bv.y, bv.z, bv.w};
      #pragma unroll
      for (int i = 0; i < 4; i++)
        #pragma unroll
        for (int j = 0; j < 4; j++)
          acc[i][j] = fmaf(a_[i], b_[j], acc[i][j]);
    }
    __syncthreads();
  }

  float4 lp = *(const float4*)&logpc[col0 + (tx << 2)];
  float lpv[4] = {lp.x, lp.y, lp.z, lp.w};
  #pragma unroll
  for (int i = 0; i < 4; i++) {
    float4 o;
    o.x = acc[i][0] + lpv[0];
    o.y = acc[i][1] + lpv[1];
    o.z = acc[i][2] + lpv[2];
    o.w = acc[i][3] + lpv[3];
    *(float4*)&scores[(row0 + (ty << 2) + i) * (size_t)MMEM + col0 + (tx << 2)] = o;
  }
}

// ---------------- kernel 4: per-row exact top-256 + weighted ratio --------
// One block per row. 8192-bin LDS histogram on top-13 key bits; exact sort
// of the cutoff bin's candidates; accumulate sum_p and sum_vp of top-256.
#define CAND_CAP 4096
__global__ __launch_bounds__(512) void select_kernel(const float* __restrict__ scores,
                                                     const float* __restrict__ values,
                                                     float* __restrict__ out) {
  __shared__ uint32_t hist[8192];
  __shared__ uint32_t csum[128];
  __shared__ float red_p[8], red_vp[8];
  __shared__ int s_bstar, s_above, s_ccount;
  float* cand_s = (float*)hist;            // overlay after histogram use
  int*   cand_i = (int*)(hist + CAND_CAP);

  const int tid = threadIdx.x;
  const int row = blockIdx.x;
  const float4* srow4 = (const float4*)(scores + (size_t)row * MMEM);

  for (int i = tid; i < 8192; i += 512) hist[i] = 0;
  if (tid == 0) s_ccount = 0;
  __syncthreads();

  // pass 1: histogram
  for (int i = tid; i < MMEM / 4; i += 512) {
    float4 v = srow4[i];
    atomicAdd(&hist[fkey(v.x) >> 19], 1u);
    atomicAdd(&hist[fkey(v.y) >> 19], 1u);
    atomicAdd(&hist[fkey(v.z) >> 19], 1u);
    atomicAdd(&hist[fkey(v.w) >> 19], 1u);
  }
  __syncthreads();

  // chunk sums for fast top-down scan
  if (tid < 128) {
    uint32_t s = 0;
    for (int b = 0; b < 64; b++) s += hist[tid * 64 + b];
    csum[tid] = s;
  }
  __syncthreads();
  if (tid == 0) {
    uint32_t cum = 0, above = 0;
    int bstar = 0;
    for (int c = 127; c >= 0; c--) {
      if (cum + csum[c] >= TOPK) {
        for (int b = 63; b >= 0; b--) {
          uint32_t h = hist[c * 64 + b];
          if (cum + h >= TOPK) { bstar = c * 64 + b; above = cum; goto found; }
          cum += h;
        }
      }
      cum += csum[c];
    }
  found:
    s_bstar = bstar;
    s_above = (int)above;
  }
  __syncthreads();
  const int bstar = s_bstar;
  const int rneed = TOPK - s_above;   // >= 1, <= 256

  // pass 2: accumulate strictly-above bins; collect cutoff-bin candidates
  float psum = 0.f, vpsum = 0.f;
  for (int i = tid; i < MMEM / 4; i += 512) {
    float4 v = srow4[i];
    float vv[4] = {v.x, v.y, v.z, v.w};
    #pragma unroll
    for (int c = 0; c < 4; c++) {
      float val = vv[c];
      int b = (int)(fkey(val) >> 19);
      if (b > bstar) {
        float p = __expf(val);
        psum += p;
        vpsum += p * values[i * 4 + c];
      } else if (b == bstar) {
        int pos = atomicAdd(&s_ccount, 1);
        if (pos < CAND_CAP) { cand_s[pos] = val; cand_i[pos] = i * 4 + c; }
      }
    }
  }
  __syncthreads();

  int c2 = s_ccount;
  if (c2 > CAND_CAP) c2 = CAND_CAP;
  int n2 = 1;
  while (n2 < c2) n2 <<= 1;
  for (int i = c2 + tid; i < n2; i += 512) { cand_s[i] = -INFINITY; cand_i[i] = 0x7FFFFFFF; }
  __syncthreads();

  // bitonic sort descending by (score, then smaller index first)
  for (int size = 2; size <= n2; size <<= 1) {
    for (int stride = size >> 1; stride > 0; stride >>= 1) {
      for (int i = tid; i < n2; i += 512) {
        int j = i ^ stride;
        if (j > i) {
          float si = cand_s[i], sj = cand_s[j];
          int ii = cand_i[i], ij = cand_i[j];
          bool igt = (si > sj) || (si == sj && ii < ij);
          bool desc = ((i & size) == 0);
          if (desc ? !igt : igt) {
            cand_s[i] = sj; cand_s[j] = si;
            cand_i[i] = ij; cand_i[j] = ii;
          }
        }
      }
      __syncthreads();
    }
  }

  int take = rneed < n2 ? rneed : n2;
  for (int i = tid; i < take; i += 512) {
    float sv = cand_s[i];
    if (sv != -INFINITY) {
      float p = __expf(sv);
      psum += p;
      vpsum += p * values[cand_i[i]];
    }
  }

  // final reduction
  #pragma unroll
  for (int off = 32; off > 0; off >>= 1) {
    psum  += __shfl_down(psum, off);
    vpsum += __shfl_down(vpsum, off);
  }
  int lane = tid & 63, wid = tid >> 6;
  if (lane == 0) { red_p[wid] = psum; red_vp[wid] = vpsum; }
  __syncthreads();
  if (tid == 0) {
    float P = 0.f, V = 0.f;
    for (int w = 0; w < 8; w++) { P += red_p[w]; V += red_vp[w]; }
    float r = V / P;
    r = fminf(fmaxf(r, 1e-3f), 1.0f - 1e-3f);
    out[row] = r;
  }
}

extern "C" void kernel_launch(void* const* d_in, const int* in_sizes, int n_in,
                              void* d_out, int out_size, void* d_ws, size_t ws_size,
                              hipStream_t stream) {
  const float* q      = (const float*)d_in[0];  // [1024, 256]
  const float* mk     = (const float*)d_in[1];  // [131072, 256]
  const float* values = (const float*)d_in[2];  // [131072]
  const float* hist   = (const float*)d_in[3];  // [131072]
  float* out = (float*)d_out;                   // [1024]

  // workspace layout:
  //   [0]       float sum
  //   [256]     float logpc[131072]           (524288 B)
  //   [524544]  float scores[rows_chunk*131072]
  float* ws_sum = (float*)d_ws;
  float* logpc  = (float*)((char*)d_ws + 256);
  float* scores = (float*)((char*)d_ws + 524544);

  // Adapt scores-chunk size to the workspace we actually have.
  // (Round 1 crash diagnosis: 512.5 MiB unconditional layout overran d_ws.)
  int rows_chunk = 64;
  for (int rc = 1024; rc >= 64; rc >>= 1) {
    if ((size_t)rc * (size_t)MMEM * 4ull + 524544ull <= ws_size) { rows_chunk = rc; break; }
  }

  hist_sum_kernel<<<1, 256, 0, stream>>>(hist, ws_sum);
  logpc_kernel<<<MMEM / 256, 256, 0, stream>>>(hist, ws_sum, logpc);
  for (int r0 = 0; r0 < NB; r0 += rows_chunk) {
    gemm_kernel<<<dim3(rows_chunk / 64, MMEM / 64), 256, 0, stream>>>(
        q + (size_t)r0 * KDIM, mk, logpc, scores);
    select_kernel<<<rows_chunk, 512, 0, stream>>>(scores, values, out + r0);
  }
}

// Round 3
// 1031.936 us; speedup vs baseline: 1.7132x; 1.7132x over previous
//
#include <hip/hip_runtime.h>
#include <math.h>
#include <stdint.h>

#define MMEM 131072
#define KDIM 256
#define NB   1024
#define TOPK 256
#define BETA_F 1e-08f

typedef _Float16 f16x8 __attribute__((ext_vector_type(8)));
typedef float    f32x4 __attribute__((ext_vector_type(4)));

// Monotone key: unsigned ascending == float ascending
__device__ __forceinline__ uint32_t fkey(float f) {
  uint32_t u = __float_as_uint(f);
  return u ^ ((uint32_t)((int32_t)u >> 31) | 0x80000000u);
}

__device__ __forceinline__ void gload16(const void* g, void* l) {
  __builtin_amdgcn_global_load_lds(
      (const __attribute__((address_space(1))) uint32_t*)g,
      (__attribute__((address_space(3))) uint32_t*)l, 16, 0, 0);
}

// ---------------- fp32 -> fp16 conversion (vectorized) --------------------
__global__ __launch_bounds__(256) void cvt_f16_kernel(const float* __restrict__ in,
                                                      _Float16* __restrict__ out, int n4) {
  int i = blockIdx.x * 256 + threadIdx.x;
  if (i < n4) {
    float4 v = *(const float4*)&in[i * 4];
    union { _Float16 h[4]; uint2 u; } p;
    p.h[0] = (_Float16)v.x; p.h[1] = (_Float16)v.y;
    p.h[2] = (_Float16)v.z; p.h[3] = (_Float16)v.w;
    *(uint2*)&out[i * 4] = p.u;
  }
}

// ---------------- sum(hist + beta), single block --------------------------
__global__ __launch_bounds__(256) void hist_sum_kernel(const float* __restrict__ hist,
                                                       float* __restrict__ out_sum) {
  float s = 0.f;
  for (int i = threadIdx.x; i < MMEM; i += 256) s += hist[i] + BETA_F;
  #pragma unroll
  for (int off = 32; off > 0; off >>= 1) s += __shfl_down(s, off);
  __shared__ float ws[4];
  int lane = threadIdx.x & 63, wid = threadIdx.x >> 6;
  if (lane == 0) ws[wid] = s;
  __syncthreads();
  if (threadIdx.x == 0) {
    float t = 0.f;
    for (int w = 0; w < 4; w++) t += ws[w];
    *out_sum = t;
  }
}

// ---------------- logpc[m] = log(hist[m]+beta) - log(sum) -----------------
__global__ __launch_bounds__(256) void logpc_kernel(const float* __restrict__ hist,
                                                    const float* __restrict__ sum_ptr,
                                                    float* __restrict__ logpc) {
  int i = blockIdx.x * 256 + threadIdx.x;
  if (i < MMEM) logpc[i] = logf(hist[i] + BETA_F) - logf(*sum_ptr);
}

// ---------------- MFMA GEMM: scores = q @ mk^T + logpc (fp16 inputs) ------
// 128x128 block tile, 256 threads = 4 waves, each wave 64x64 via 4x4 of
// 16x16x32 MFMAs. BK=64. Staging via global_load_lds width=16 with XOR
// swizzle applied to the SOURCE address (LDS dest must be lane-contiguous).
// LDS slot [r][c] (c = 16B chunk 0..7) holds global chunk (c ^ (r&7)).
__global__ __launch_bounds__(256) void gemm_kernel(const _Float16* __restrict__ qh,
                                                   const _Float16* __restrict__ mkh,
                                                   const float* __restrict__ logpc,
                                                   float* __restrict__ scores) {
  __shared__ _Float16 As[128 * 64];   // 16 KB
  __shared__ _Float16 Bs[128 * 64];   // 16 KB

  const int t    = threadIdx.x;
  const int lane = t & 63;
  const int wave = t >> 6;
  const int wr   = (wave & 1) * 64;   // wave row offset in tile
  const int wc   = (wave >> 1) * 64;  // wave col offset in tile
  const int lm   = lane & 15;
  const int lk   = lane >> 4;         // 0..3
  const int row0 = blockIdx.x * 128;  // chunk-local rows
  const int col0 = blockIdx.y * 128;  // over M

  const int tr = t >> 3;              // 0..31 (row within staging issue)
  const int tc = t & 7;               // chunk slot
  const int gc = tc ^ (tr & 7);       // swizzled source chunk

  f32x4 acc[4][4];
  #pragma unroll
  for (int i = 0; i < 4; i++)
    #pragma unroll
    for (int j = 0; j < 4; j++)
      acc[i][j] = (f32x4){0.f, 0.f, 0.f, 0.f};

  for (int kb = 0; kb < KDIM; kb += 64) {
    // stage A (q rows) and B (mk rows): 4 issues each of 256 lanes x 16 B
    #pragma unroll
    for (int is = 0; is < 4; is++) {
      int r = is * 32 + tr;
      const char* ga = (const char*)qh + ((size_t)(row0 + r) * KDIM + kb) * 2 + gc * 16;
      gload16(ga, (char*)As + is * 4096 + t * 16);
    }
    #pragma unroll
    for (int is = 0; is < 4; is++) {
      int r = is * 32 + tr;
      const char* gb = (const char*)mkh + ((size_t)(col0 + r) * KDIM + kb) * 2 + gc * 16;
      gload16(gb, (char*)Bs + is * 4096 + t * 16);
    }
    __syncthreads();

    #pragma unroll
    for (int s = 0; s < 2; s++) {
      f16x8 af[4], bf[4];
      #pragma unroll
      for (int i = 0; i < 4; i++) {
        int ar = wr + i * 16 + lm;
        int c  = (s * 4 + lk) ^ (ar & 7);
        af[i] = *(const f16x8*)((const char*)As + ar * 128 + c * 16);
      }
      #pragma unroll
      for (int j = 0; j < 4; j++) {
        int br = wc + j * 16 + lm;
        int c  = (s * 4 + lk) ^ (br & 7);
        bf[j] = *(const f16x8*)((const char*)Bs + br * 128 + c * 16);
      }
      #pragma unroll
      for (int i = 0; i < 4; i++)
        #pragma unroll
        for (int j = 0; j < 4; j++)
          acc[i][j] = __builtin_amdgcn_mfma_f32_16x16x32_f16(af[i], bf[j], acc[i][j], 0, 0, 0);
    }
    __syncthreads();
  }

  // epilogue: D mapping (m89-verified): col = lane&15, row = (lane>>4)*4 + reg
  #pragma unroll
  for (int j = 0; j < 4; j++) {
    int col = col0 + wc + j * 16 + lm;
    float lp = logpc[col];
    #pragma unroll
    for (int i = 0; i < 4; i++) {
      int rbase = row0 + wr + i * 16 + lk * 4;
      #pragma unroll
      for (int r4 = 0; r4 < 4; r4++)
        scores[(size_t)(rbase + r4) * MMEM + col] = acc[i][j][r4] + lp;
    }
  }
}

// ---------------- per-row exact top-256 + weighted ratio ------------------
#define CAND_CAP 4096
__global__ __launch_bounds__(512) void select_kernel(const float* __restrict__ scores,
                                                     const float* __restrict__ values,
                                                     float* __restrict__ out) {
  __shared__ uint32_t hist[8192];
  __shared__ uint32_t csum[128];
  __shared__ float red_p[8], red_vp[8];
  __shared__ int s_bstar, s_above, s_ccount;
  float* cand_s = (float*)hist;            // overlay after histogram use
  int*   cand_i = (int*)(hist + CAND_CAP);

  const int tid = threadIdx.x;
  const int row = blockIdx.x;
  const float4* srow4 = (const float4*)(scores + (size_t)row * MMEM);

  for (int i = tid; i < 8192; i += 512) hist[i] = 0;
  if (tid == 0) s_ccount = 0;
  __syncthreads();

  for (int i = tid; i < MMEM / 4; i += 512) {
    float4 v = srow4[i];
    atomicAdd(&hist[fkey(v.x) >> 19], 1u);
    atomicAdd(&hist[fkey(v.y) >> 19], 1u);
    atomicAdd(&hist[fkey(v.z) >> 19], 1u);
    atomicAdd(&hist[fkey(v.w) >> 19], 1u);
  }
  __syncthreads();

  if (tid < 128) {
    uint32_t s = 0;
    for (int b = 0; b < 64; b++) s += hist[tid * 64 + b];
    csum[tid] = s;
  }
  __syncthreads();
  if (tid == 0) {
    uint32_t cum = 0, above = 0;
    int bstar = 0;
    for (int c = 127; c >= 0; c--) {
      if (cum + csum[c] >= TOPK) {
        for (int b = 63; b >= 0; b--) {
          uint32_t h = hist[c * 64 + b];
          if (cum + h >= TOPK) { bstar = c * 64 + b; above = cum; goto found; }
          cum += h;
        }
      }
      cum += csum[c];
    }
  found:
    s_bstar = bstar;
    s_above = (int)above;
  }
  __syncthreads();
  const int bstar = s_bstar;
  const int rneed = TOPK - s_above;

  float psum = 0.f, vpsum = 0.f;
  for (int i = tid; i < MMEM / 4; i += 512) {
    float4 v = srow4[i];
    float vv[4] = {v.x, v.y, v.z, v.w};
    #pragma unroll
    for (int c = 0; c < 4; c++) {
      float val = vv[c];
      int b = (int)(fkey(val) >> 19);
      if (b > bstar) {
        float p = __expf(val);
        psum += p;
        vpsum += p * values[i * 4 + c];
      } else if (b == bstar) {
        int pos = atomicAdd(&s_ccount, 1);
        if (pos < CAND_CAP) { cand_s[pos] = val; cand_i[pos] = i * 4 + c; }
      }
    }
  }
  __syncthreads();

  int c2 = s_ccount;
  if (c2 > CAND_CAP) c2 = CAND_CAP;
  int n2 = 1;
  while (n2 < c2) n2 <<= 1;
  for (int i = c2 + tid; i < n2; i += 512) { cand_s[i] = -INFINITY; cand_i[i] = 0x7FFFFFFF; }
  __syncthreads();

  for (int size = 2; size <= n2; size <<= 1) {
    for (int stride = size >> 1; stride > 0; stride >>= 1) {
      for (int i = tid; i < n2; i += 512) {
        int j = i ^ stride;
        if (j > i) {
          float si = cand_s[i], sj = cand_s[j];
          int ii = cand_i[i], ij = cand_i[j];
          bool igt = (si > sj) || (si == sj && ii < ij);
          bool desc = ((i & size) == 0);
          if (desc ? !igt : igt) {
            cand_s[i] = sj; cand_s[j] = si;
            cand_i[i] = ij; cand_i[j] = ii;
          }
        }
      }
      __syncthreads();
    }
  }

  int take = rneed < n2 ? rneed : n2;
  for (int i = tid; i < take; i += 512) {
    float sv = cand_s[i];
    if (sv != -INFINITY) {
      float p = __expf(sv);
      psum += p;
      vpsum += p * values[cand_i[i]];
    }
  }

  #pragma unroll
  for (int off = 32; off > 0; off >>= 1) {
    psum  += __shfl_down(psum, off);
    vpsum += __shfl_down(vpsum, off);
  }
  int lane = tid & 63, wid = tid >> 6;
  if (lane == 0) { red_p[wid] = psum; red_vp[wid] = vpsum; }
  __syncthreads();
  if (tid == 0) {
    float P = 0.f, V = 0.f;
    for (int w = 0; w < 8; w++) { P += red_p[w]; V += red_vp[w]; }
    float r = V / P;
    r = fminf(fmaxf(r, 1e-3f), 1.0f - 1e-3f);
    out[row] = r;
  }
}

extern "C" void kernel_launch(void* const* d_in, const int* in_sizes, int n_in,
                              void* d_out, int out_size, void* d_ws, size_t ws_size,
                              hipStream_t stream) {
  const float* q      = (const float*)d_in[0];  // [1024, 256]
  const float* mk     = (const float*)d_in[1];  // [131072, 256]
  const float* values = (const float*)d_in[2];  // [131072]
  const float* hist   = (const float*)d_in[3];  // [131072]
  float* out = (float*)d_out;                   // [1024]

  // workspace layout:
  //   [0]        float sum
  //   [256]      float    logpc[131072]          (524288 B)
  //   [524544]   _Float16 qh[1024*256]           (524288 B)
  //   [1048832]  _Float16 mkh[131072*256]        (67108864 B)
  //   [68157696] float    scores[rc*131072]
  float*    ws_sum = (float*)d_ws;
  float*    logpc  = (float*)((char*)d_ws + 256);
  _Float16* qh     = (_Float16*)((char*)d_ws + 524544);
  _Float16* mkh    = (_Float16*)((char*)d_ws + 1048832);
  float*    scores = (float*)((char*)d_ws + 68157696ull);

  // rc=256 keeps scores chunk (134 MB) + mkh (67 MB) LLC-resident.
  int rows_chunk = 64;
  for (int rc = 256; rc >= 64; rc >>= 1) {
    if (68157696ull + (size_t)rc * MMEM * 4ull <= ws_size) { rows_chunk = rc; break; }
  }

  cvt_f16_kernel<<<(NB * KDIM / 4) / 256, 256, 0, stream>>>(q, qh, NB * KDIM / 4);
  cvt_f16_kernel<<<((size_t)MMEM * KDIM / 4) / 256, 256, 0, stream>>>(mk, mkh, MMEM * KDIM / 4);
  hist_sum_kernel<<<1, 256, 0, stream>>>(hist, ws_sum);
  logpc_kernel<<<MMEM / 256, 256, 0, stream>>>(hist, ws_sum, logpc);

  for (int r0 = 0; r0 < NB; r0 += rows_chunk) {
    gemm_kernel<<<dim3(rows_chunk / 128, MMEM / 128), 256, 0, stream>>>(
        qh + (size_t)r0 * KDIM, mkh, logpc, scores);
    select_kernel<<<rows_chunk, 512, 0, stream>>>(scores, values, out + r0);
  }
}